// Round 1
// baseline (8235.183 us; speedup 1.0000x reference)
//
#include <hip/hip_runtime.h>
#include <hip/hip_bf16.h>

#define T_STEPS 24
#define NSLOPE 0.2f

__device__ __forceinline__ float sigm(float x){ return 1.0f/(1.0f+__expf(-x)); }
__device__ __forceinline__ float tanh_f(float x){ return 2.0f/(1.0f+__expf(-2.0f*x)) - 1.0f; }

// monotone float<->uint encoding for atomicMax on floats
__device__ __forceinline__ unsigned fenc(float f){ unsigned u = __float_as_uint(f); return (u & 0x80000000u) ? ~u : (u | 0x80000000u); }
__device__ __forceinline__ float fdec(unsigned k){ return (k & 0x80000000u) ? __uint_as_float(k & 0x7fffffffu) : __uint_as_float(~k); }

// ---------------- prep: transpose/interleave weights, fold biases, edge consts, mask-dtype flag ----------------
__global__ __launch_bounds__(256) void prep_kernel(
    const float* __restrict__ W_ih1, const float* __restrict__ W_hh1,
    const float* __restrict__ b_ih1, const float* __restrict__ b_hh1,
    const float* __restrict__ W_ih2, const float* __restrict__ W_hh2,
    const float* __restrict__ b_ih2, const float* __restrict__ b_hh2,
    const float* __restrict__ glw, const float* __restrict__ glew,
    const float* __restrict__ atte, const unsigned char* __restrict__ mask_bytes,
    float* __restrict__ W1T, float* __restrict__ W2T, float* __restrict__ W3T,
    float* __restrict__ w1i, float* __restrict__ b1i, float* __restrict__ b2i,
    float* __restrict__ ke, int* __restrict__ flag)
{
    int tid = blockIdx.x*blockDim.x + threadIdx.x;
    int nth = gridDim.x*blockDim.x;
    // W1T[k*256 + j*4 + g] = W_hh1[(g*64+j)*64 + k]   (transposed, gate-interleaved)
    for (int i = tid; i < 64*256; i += nth){ int k = i>>8, r = i&255; int j = r>>2, g = r&3; W1T[i] = W_hh1[(g*64+j)*64 + k]; }
    // W2T: k<64 -> W_ih2 (input h1), k>=64 -> W_hh2 (recurrent h2)
    for (int i = tid; i < 128*256; i += nth){ int k = i>>8, r = i&255; int j = r>>2, g = r&3; int row = g*64+j;
        W2T[i] = (k < 64) ? W_ih2[row*64 + k] : W_hh2[row*64 + (k-64)]; }
    // W3T[k*64 + r] = gat_lin_w[r*64 + k]
    for (int i = tid; i < 64*64; i += nth){ int k = i>>6, r = i&63; W3T[i] = glw[r*64 + k]; }
    for (int i = tid; i < 256; i += nth){ int j = i>>2, g = i&3; int row = g*64+j;
        w1i[i] = W_ih1[row]; b1i[i] = b_ih1[row]+b_hh1[row]; b2i[i] = b_ih2[row]+b_hh2[row]; }
    if (tid < 4){ float s = 0.f; for (int c = 0; c < 16; c++) s += atte[tid*16+c]*glew[tid*16+c]; ke[tid] = s; }
    if (tid == 0){ // detect mask storage: int32 (bytes at off%4!=0 all zero) vs 1-byte bool
        int nz = 0;
        for (int i = 0; i < 4096; i++){ if ((i&3) != 0 && mask_bytes[i] != 0) nz++; }
        *flag = (nz == 0) ? 1 : 0;   // 1 => int32 mask
    }
}

// ---------------- fused 2-layer LSTM over T steps + GAT linear projection + att dots ----------------
// block = 256 threads = 4 waves; each wave owns 16 nodes for all 24 steps.
// lane j owns channel j: computes gate rows {g*64+j}; h-state lives in LDS, c-state in regs.
__global__ __launch_bounds__(256) void lstm_kernel(
    const float* __restrict__ x_in,
    const float* __restrict__ W1T, const float* __restrict__ W2T, const float* __restrict__ W3T,
    const float* __restrict__ w1i, const float* __restrict__ b1i, const float* __restrict__ b2i,
    const float* __restrict__ atts, const float* __restrict__ attd,
    float* __restrict__ x_out, float* __restrict__ a_src, float* __restrict__ a_dst, int nn)
{
    __shared__ float hbuf[64][128];   // [node-in-block][h1(0..63) | h2(64..127)]
    const int wave = threadIdx.x >> 6;
    const int lane = threadIdx.x & 63;
    const int nb0 = wave * 16;
    const int node0 = blockIdx.x * 64 + nb0;

    const float4 b1r = *(const float4*)(b1i + lane*4);
    const float4 w1r = *(const float4*)(w1i + lane*4);
    const float4 b2r = *(const float4*)(b2i + lane*4);

    float c1[16], c2[16];
    #pragma unroll
    for (int n = 0; n < 16; n++){ c1[n]=0.f; c2[n]=0.f; hbuf[nb0+n][lane]=0.f; hbuf[nb0+n][64+lane]=0.f; }

    float acc[16][4];
    for (int t = 0; t < T_STEPS; t++){
        // ----- layer 1: z1 = h1 @ W_hh1^T + x_t*w_ih1 + b1 -----
        #pragma unroll
        for (int n = 0; n < 16; n++){
            int nd = node0 + n;
            float xv = (nd < nn) ? x_in[nd*T_STEPS + t] : 0.f;
            acc[n][0] = b1r.x + xv*w1r.x;
            acc[n][1] = b1r.y + xv*w1r.y;
            acc[n][2] = b1r.z + xv*w1r.z;
            acc[n][3] = b1r.w + xv*w1r.w;
        }
        for (int k = 0; k < 64; k += 4){
            float4 wa = *(const float4*)(W1T + (k+0)*256 + lane*4);
            float4 wb = *(const float4*)(W1T + (k+1)*256 + lane*4);
            float4 wc = *(const float4*)(W1T + (k+2)*256 + lane*4);
            float4 wd = *(const float4*)(W1T + (k+3)*256 + lane*4);
            #pragma unroll
            for (int n = 0; n < 16; n++){
                float4 h = *(const float4*)&hbuf[nb0+n][k];
                acc[n][0] += h.x*wa.x + h.y*wb.x + h.z*wc.x + h.w*wd.x;
                acc[n][1] += h.x*wa.y + h.y*wb.y + h.z*wc.y + h.w*wd.y;
                acc[n][2] += h.x*wa.z + h.y*wb.z + h.z*wc.z + h.w*wd.z;
                acc[n][3] += h.x*wa.w + h.y*wb.w + h.z*wc.w + h.w*wd.w;
            }
        }
        #pragma unroll
        for (int n = 0; n < 16; n++){
            float gi = sigm(acc[n][0]);
            float gf = sigm(acc[n][1]);
            float gg = tanh_f(acc[n][2]);
            float go = sigm(acc[n][3]);
            c1[n] = gf*c1[n] + gi*gg;
            hbuf[nb0+n][lane] = go * tanh_f(c1[n]);
        }
        // ----- layer 2: z2 = [h1;h2] @ [W_ih2;W_hh2]^T + b2 -----
        #pragma unroll
        for (int n = 0; n < 16; n++){
            acc[n][0] = b2r.x; acc[n][1] = b2r.y; acc[n][2] = b2r.z; acc[n][3] = b2r.w;
        }
        for (int k = 0; k < 128; k += 4){
            float4 wa = *(const float4*)(W2T + (k+0)*256 + lane*4);
            float4 wb = *(const float4*)(W2T + (k+1)*256 + lane*4);
            float4 wc = *(const float4*)(W2T + (k+2)*256 + lane*4);
            float4 wd = *(const float4*)(W2T + (k+3)*256 + lane*4);
            #pragma unroll
            for (int n = 0; n < 16; n++){
                float4 h = *(const float4*)&hbuf[nb0+n][k];
                acc[n][0] += h.x*wa.x + h.y*wb.x + h.z*wc.x + h.w*wd.x;
                acc[n][1] += h.x*wa.y + h.y*wb.y + h.z*wc.y + h.w*wd.y;
                acc[n][2] += h.x*wa.z + h.y*wb.z + h.z*wc.z + h.w*wd.z;
                acc[n][3] += h.x*wa.w + h.y*wb.w + h.z*wc.w + h.w*wd.w;
            }
        }
        #pragma unroll
        for (int n = 0; n < 16; n++){
            float gi = sigm(acc[n][0]);
            float gf = sigm(acc[n][1]);
            float gg = tanh_f(acc[n][2]);
            float go = sigm(acc[n][3]);
            c2[n] = gf*c2[n] + gi*gg;
            hbuf[nb0+n][64+lane] = go * tanh_f(c2[n]);
        }
    }

    // ----- GAT projection: x = h2 @ gat_lin_w^T (64->64), plus a_src/a_dst dots -----
    float pacc[16];
    #pragma unroll
    for (int n = 0; n < 16; n++) pacc[n] = 0.f;
    for (int k = 0; k < 64; k += 4){
        float w0 = W3T[(k+0)*64 + lane];
        float w1 = W3T[(k+1)*64 + lane];
        float w2 = W3T[(k+2)*64 + lane];
        float w3 = W3T[(k+3)*64 + lane];
        #pragma unroll
        for (int n = 0; n < 16; n++){
            float4 h = *(const float4*)&hbuf[nb0+n][64+k];
            pacc[n] += h.x*w0 + h.y*w1 + h.z*w2 + h.w*w3;
        }
    }
    float asw = atts[lane], adw = attd[lane];  // att_src/att_dst flat (4,16) matches channel=lane
    #pragma unroll
    for (int n = 0; n < 16; n++){
        int nd = node0 + n;
        float xv = pacc[n];
        float sv = xv * asw, dv = xv * adw;
        #pragma unroll
        for (int off = 1; off < 16; off <<= 1){ sv += __shfl_xor(sv, off, 16); dv += __shfl_xor(dv, off, 16); }
        if (nd < nn){
            x_out[(size_t)nd*64 + lane] = xv;
            if ((lane & 15) == 0){ int h = lane >> 4; a_src[nd*4 + h] = sv; a_dst[nd*4 + h] = dv; }
        }
    }
}

// ---------------- edge pass 1: segment max of leaky_relu(alpha) via atomicMax ----------------
__global__ __launch_bounds__(256) void edge_max_kernel(
    const int* __restrict__ ei, const float* __restrict__ ea, const void* __restrict__ maskp,
    const int* __restrict__ flag, const float* __restrict__ a_src, const float* __restrict__ a_dst,
    const float* __restrict__ ke, unsigned* __restrict__ amax, int E)
{
    int e = blockIdx.x*256 + threadIdx.x;
    if (e >= E) return;
    bool m = (*flag) ? (((const int*)maskp)[e] != 0) : (((const unsigned char*)maskp)[e] != 0);
    if (!m) return;
    int s = ei[e], d = ei[E + e];
    float eav = ea[e];
    float4 as4 = *(const float4*)(a_src + 4*s);
    float4 ad4 = *(const float4*)(a_dst + 4*d);
    float a0 = as4.x + ad4.x + eav*ke[0]; a0 = a0 > 0.f ? a0 : NSLOPE*a0;
    float a1 = as4.y + ad4.y + eav*ke[1]; a1 = a1 > 0.f ? a1 : NSLOPE*a1;
    float a2 = as4.z + ad4.z + eav*ke[2]; a2 = a2 > 0.f ? a2 : NSLOPE*a2;
    float a3 = as4.w + ad4.w + eav*ke[3]; a3 = a3 > 0.f ? a3 : NSLOPE*a3;
    atomicMax(amax + 4*d + 0, fenc(a0));
    atomicMax(amax + 4*d + 1, fenc(a1));
    atomicMax(amax + 4*d + 2, fenc(a2));
    atomicMax(amax + 4*d + 3, fenc(a3));
}

// ---------------- edge pass 2: ex = exp(alpha - amax[dst]); denom += ex ----------------
__global__ __launch_bounds__(256) void edge_ex_kernel(
    const int* __restrict__ ei, const float* __restrict__ ea, const void* __restrict__ maskp,
    const int* __restrict__ flag, const float* __restrict__ a_src, const float* __restrict__ a_dst,
    const float* __restrict__ ke, const unsigned* __restrict__ amax,
    float* __restrict__ denom, float* __restrict__ exb, int E)
{
    int e = blockIdx.x*256 + threadIdx.x;
    if (e >= E) return;
    float4 exv = make_float4(0.f, 0.f, 0.f, 0.f);
    bool m = (*flag) ? (((const int*)maskp)[e] != 0) : (((const unsigned char*)maskp)[e] != 0);
    if (m){
        int s = ei[e], d = ei[E + e];
        float eav = ea[e];
        float4 as4 = *(const float4*)(a_src + 4*s);
        float4 ad4 = *(const float4*)(a_dst + 4*d);
        float a0 = as4.x + ad4.x + eav*ke[0]; a0 = a0 > 0.f ? a0 : NSLOPE*a0;
        float a1 = as4.y + ad4.y + eav*ke[1]; a1 = a1 > 0.f ? a1 : NSLOPE*a1;
        float a2 = as4.z + ad4.z + eav*ke[2]; a2 = a2 > 0.f ? a2 : NSLOPE*a2;
        float a3 = as4.w + ad4.w + eav*ke[3]; a3 = a3 > 0.f ? a3 : NSLOPE*a3;
        exv.x = __expf(a0 - fdec(amax[4*d + 0]));
        exv.y = __expf(a1 - fdec(amax[4*d + 1]));
        exv.z = __expf(a2 - fdec(amax[4*d + 2]));
        exv.w = __expf(a3 - fdec(amax[4*d + 3]));
        atomicAdd(denom + 4*d + 0, exv.x);
        atomicAdd(denom + 4*d + 1, exv.y);
        atomicAdd(denom + 4*d + 2, exv.z);
        atomicAdd(denom + 4*d + 3, exv.w);
    }
    *(float4*)(exb + 4*(size_t)e) = exv;
}

// ---------------- edge pass 3: out[dst] += ex * x[src]  (16 lanes per edge, 4 ch each) ----------------
__global__ __launch_bounds__(256) void edge_msg_kernel(
    const int* __restrict__ ei, const float* __restrict__ exb, const float* __restrict__ xf,
    float* __restrict__ outb, int E)
{
    int t = blockIdx.x*256 + threadIdx.x;
    int e = t >> 4;
    int l = t & 15;
    if (e >= E) return;
    float ev = exb[4*(size_t)e + (l >> 2)];
    if (ev == 0.f) return;
    int s = ei[e], d = ei[E + e];
    float4 xv = *(const float4*)(xf + 64*(size_t)s + 4*l);
    atomicAdd(outb + 64*(size_t)d + 4*l + 0, xv.x*ev);
    atomicAdd(outb + 64*(size_t)d + 4*l + 1, xv.y*ev);
    atomicAdd(outb + 64*(size_t)d + 4*l + 2, xv.z*ev);
    atomicAdd(outb + 64*(size_t)d + 4*l + 3, xv.w*ev);
}

// ---------------- finalize: normalize, +bias, elu, fc dot ----------------
__global__ __launch_bounds__(256) void finalize_kernel(
    const float* __restrict__ outb, const float* __restrict__ denom,
    const float* __restrict__ gbias, const float* __restrict__ fcw, const float* __restrict__ fcb,
    float* __restrict__ y, int nn)
{
    int wave = threadIdx.x >> 6, lane = threadIdx.x & 63;
    int node = blockIdx.x*4 + wave;
    if (node >= nn) return;
    float den = fmaxf(denom[node*4 + (lane >> 4)], 1e-16f);
    float v = outb[64*(size_t)node + lane] / den + gbias[lane];
    v = v > 0.f ? v : (__expf(v) - 1.f);
    float acc = v * fcw[lane];
    #pragma unroll
    for (int off = 1; off < 64; off <<= 1) acc += __shfl_xor(acc, off, 64);
    if (lane == 0) y[node] = acc + fcb[0];
}

extern "C" void kernel_launch(void* const* d_in, const int* in_sizes, int n_in,
                              void* d_out, int out_size, void* d_ws, size_t ws_size,
                              hipStream_t stream)
{
    const float* x_in  = (const float*)d_in[0];
    const int*   ei    = (const int*)d_in[1];
    const float* ea    = (const float*)d_in[2];
    const void*  mask  = d_in[3];
    const float* W_ih1 = (const float*)d_in[4];
    const float* W_hh1 = (const float*)d_in[5];
    const float* b_ih1 = (const float*)d_in[6];
    const float* b_hh1 = (const float*)d_in[7];
    const float* W_ih2 = (const float*)d_in[8];
    const float* W_hh2 = (const float*)d_in[9];
    const float* b_ih2 = (const float*)d_in[10];
    const float* b_hh2 = (const float*)d_in[11];
    const float* glw   = (const float*)d_in[12];
    const float* glew  = (const float*)d_in[13];
    const float* atts  = (const float*)d_in[14];
    const float* attd  = (const float*)d_in[15];
    const float* atte  = (const float*)d_in[16];
    const float* gbias = (const float*)d_in[17];
    const float* fcw   = (const float*)d_in[18];
    const float* fcb   = (const float*)d_in[19];

    const int NN = in_sizes[0] / T_STEPS;
    const int E  = in_sizes[1] / 2;

    float* ws = (float*)d_ws;
    size_t o = 0;
    float* W1T = ws + o; o += 64*256;
    float* W2T = ws + o; o += 128*256;
    float* W3T = ws + o; o += 64*64;
    float* w1i = ws + o; o += 256;
    float* b1i = ws + o; o += 256;
    float* b2i = ws + o; o += 256;
    float* ke  = ws + o; o += 64;
    int*   flag= (int*)(ws + o); o += 64;
    float* asrc= ws + o; o += (size_t)NN*4;
    float* adst= ws + o; o += (size_t)NN*4;
    unsigned* amax = (unsigned*)(ws + o); o += (size_t)NN*4;
    float* denom = ws + o; o += (size_t)NN*4;
    float* outb  = ws + o; o += (size_t)NN*64;
    float* xf    = ws + o; o += (size_t)NN*64;
    float* exb   = ws + o; o += (size_t)E*4;

    // zero amax(keys) | denom | outb in one contiguous async memset
    hipMemsetAsync(amax, 0, ((size_t)NN*4 + (size_t)NN*4 + (size_t)NN*64)*sizeof(float), stream);

    prep_kernel<<<64, 256, 0, stream>>>(W_ih1, W_hh1, b_ih1, b_hh1, W_ih2, W_hh2, b_ih2, b_hh2,
                                        glw, glew, atte, (const unsigned char*)mask,
                                        W1T, W2T, W3T, w1i, b1i, b2i, ke, flag);
    lstm_kernel<<<(NN + 63)/64, 256, 0, stream>>>(x_in, W1T, W2T, W3T, w1i, b1i, b2i,
                                                  atts, attd, xf, asrc, adst, NN);
    edge_max_kernel<<<(E + 255)/256, 256, 0, stream>>>(ei, ea, mask, flag, asrc, adst, ke, amax, E);
    edge_ex_kernel<<<(E + 255)/256, 256, 0, stream>>>(ei, ea, mask, flag, asrc, adst, ke, amax, denom, exb, E);
    edge_msg_kernel<<<(E + 15)/16, 256, 0, stream>>>(ei, exb, xf, outb, E);
    finalize_kernel<<<(NN + 3)/4, 256, 0, stream>>>(outb, denom, gbias, fcw, fcb, (float*)d_out, NN);
}

// Round 2
// 2084.641 us; speedup vs baseline: 3.9504x; 3.9504x over previous
//
#include <hip/hip_runtime.h>
#include <hip/hip_bf16.h>

#define T_STEPS 24
#define NSLOPE 0.2f

typedef _Float16 half8 __attribute__((ext_vector_type(8)));
typedef _Float16 half4_t __attribute__((ext_vector_type(4)));
typedef float floatx4 __attribute__((ext_vector_type(4)));

__device__ __forceinline__ float sigm(float x){ return 1.0f/(1.0f+__expf(-x)); }
__device__ __forceinline__ float tanh_f(float x){ return 2.0f/(1.0f+__expf(-2.0f*x)) - 1.0f; }

// monotone float<->uint encoding for atomicMax on floats
__device__ __forceinline__ unsigned fenc(float f){ unsigned u = __float_as_uint(f); return (u & 0x80000000u) ? ~u : (u | 0x80000000u); }
__device__ __forceinline__ float fdec(unsigned k){ return (k & 0x80000000u) ? __uint_as_float(k & 0x7fffffffu) : __uint_as_float(~k); }

// ---------------- prep: build fp16 MFMA A-fragments, edge consts, mask-dtype flag ----------------
// Gate-row packing: wave w owns gate rows {gtype*64 + 16w + rt : rt=0..15, gtype=0..3} as 4 M-tiles.
// A-frag lane layout (16x16x32): row = lane&15, k = (lane>>4)*8 + b.
__global__ __launch_bounds__(256) void prep_kernel(
    const float* __restrict__ W_ih1, const float* __restrict__ W_hh1,
    const float* __restrict__ b_ih1, const float* __restrict__ b_hh1,
    const float* __restrict__ W_ih2, const float* __restrict__ W_hh2,
    const float* __restrict__ b_ih2, const float* __restrict__ b_hh2,
    const float* __restrict__ glw, const float* __restrict__ glew,
    const float* __restrict__ atte, const unsigned char* __restrict__ mask_bytes,
    _Float16* __restrict__ W1F, _Float16* __restrict__ W2F, _Float16* __restrict__ W3F,
    float* __restrict__ ke, int* __restrict__ flag)
{
    int tid = blockIdx.x*blockDim.x + threadIdx.x;
    int nth = gridDim.x*blockDim.x;
    // W1F: [w][m][kt<3][lane][b]  — layer1, K = [h1(64) | x,1,pad30]
    for (int idx = tid; idx < 24576; idx += nth){
        int b = idx & 7, t1 = idx >> 3; int lane = t1 & 63, t2 = t1 >> 6;
        int kt = t2 % 3, t3 = t2 / 3; int m = t3 & 3, w = t3 >> 2;
        int row = m*64 + 16*w + (lane & 15);
        float val;
        if (kt < 2){ val = W_hh1[row*64 + 32*kt + (lane>>4)*8 + b]; }
        else { int kin = (lane>>4)*8 + b;
               val = (kin == 0) ? W_ih1[row] : (kin == 1) ? (b_ih1[row]+b_hh1[row]) : 0.f; }
        W1F[idx] = (_Float16)val;
    }
    // W2F: [w][m][kt<5][lane][b] — layer2, K = [h1(64) | h2(64) | 1,pad31]
    for (int idx = tid; idx < 40960; idx += nth){
        int b = idx & 7, t1 = idx >> 3; int lane = t1 & 63, t2 = t1 >> 6;
        int kt = t2 % 5, t3 = t2 / 5; int m = t3 & 3, w = t3 >> 2;
        int row = m*64 + 16*w + (lane & 15);
        float val;
        if (kt < 4){ int k = 32*kt + (lane>>4)*8 + b;
                     val = (k < 64) ? W_ih2[row*64 + k] : W_hh2[row*64 + (k-64)]; }
        else { int kin = (lane>>4)*8 + b;
               val = (kin == 0) ? (b_ih2[row]+b_hh2[row]) : 0.f; }
        W2F[idx] = (_Float16)val;
    }
    // W3F: [w][kt<2][lane][b] — GAT projection, out-ch rows 16w..16w+15, K = h2(64)
    for (int idx = tid; idx < 4096; idx += nth){
        int b = idx & 7, t1 = idx >> 3; int lane = t1 & 63, t2 = t1 >> 6;
        int kt = t2 & 1, w = t2 >> 1;
        int row = 16*w + (lane & 15);
        W3F[idx] = (_Float16)glw[row*64 + 32*kt + (lane>>4)*8 + b];
    }
    if (tid < 4){ float s = 0.f; for (int c = 0; c < 16; c++) s += atte[tid*16+c]*glew[tid*16+c]; ke[tid] = s; }
    if (tid == 0){ int nz = 0;
        for (int i = 0; i < 4096; i++){ if ((i&3) != 0 && mask_bytes[i] != 0) nz++; }
        *flag = (nz == 0) ? 1 : 0; }
}

// ---------------- fused MFMA LSTM + GAT projection ----------------
// block = 256 threads = 4 waves, 64 nodes. Wave w computes gates for channels [16w,16w+16),
// ALL 64 nodes (4 N-tiles). Weights persist in VGPRs as A-frags. h via padded LDS.
__global__ __launch_bounds__(256, 2) void lstm_kernel(
    const float* __restrict__ x_in,
    const _Float16* __restrict__ W1F, const _Float16* __restrict__ W2F, const _Float16* __restrict__ W3F,
    const float* __restrict__ atts, const float* __restrict__ attd,
    float* __restrict__ x_out, float* __restrict__ a_src, float* __restrict__ a_dst, int nn)
{
    __shared__ _Float16 h_lds[64*136];   // [node][136]: ch 0..63 = h1, 64..127 = h2, pad 8
    __shared__ float    x_lds[64*25];    // [node][25] (pad 1)
    __shared__ float    xp_lds[64*68];   // projected x, [node][68] (pad 4)

    const int wv   = threadIdx.x >> 6;
    const int lane = threadIdx.x & 63;
    const int grp  = lane >> 4;
    const int col  = lane & 15;
    const int node0 = blockIdx.x * 64;

    // stage x (coalesced) and zero h
    for (int i = threadIdx.x; i < 64*T_STEPS; i += 256){
        int node = i / T_STEPS, t = i % T_STEPS;
        int nd = node0 + node;
        x_lds[node*25 + t] = (nd < nn) ? x_in[nd*T_STEPS + t] : 0.f;
    }
    for (int i = threadIdx.x; i < 64*136/2; i += 256) ((float*)h_lds)[i] = 0.f;

    // load persistent weight fragments
    const half8* W1Fv = (const half8*)W1F;
    const half8* W2Fv = (const half8*)W2F;
    half8 w1f[4][3], w2f[4][5];
    #pragma unroll
    for (int m = 0; m < 4; m++){
        #pragma unroll
        for (int kt = 0; kt < 3; kt++) w1f[m][kt] = W1Fv[((wv*4+m)*3+kt)*64 + lane];
        #pragma unroll
        for (int kt = 0; kt < 5; kt++) w2f[m][kt] = W2Fv[((wv*4+m)*5+kt)*64 + lane];
    }

    float c1s[16], c2s[16];
    #pragma unroll
    for (int i = 0; i < 16; i++){ c1s[i] = 0.f; c2s[i] = 0.f; }

    half8 cb;  // layer2 bias-tile B-frag: k=128 -> 1.0
    #pragma unroll
    for (int b = 0; b < 8; b++) cb[b] = (_Float16)0.f;
    if (grp == 0) cb[0] = (_Float16)1.0f;

    __syncthreads();

    for (int t = 0; t < T_STEPS; t++){
        // ---------- layer 1 ----------
        half4_t st1[4];
        #pragma unroll
        for (int nt = 0; nt < 4; nt++){
            int node = nt*16 + col;
            floatx4 a0 = {0,0,0,0}, a1 = {0,0,0,0}, a2 = {0,0,0,0}, a3 = {0,0,0,0};
            #pragma unroll
            for (int kt = 0; kt < 2; kt++){
                half8 bf = *(const half8*)&h_lds[node*136 + kt*32 + grp*8];
                a0 = __builtin_amdgcn_mfma_f32_16x16x32_f16(w1f[0][kt], bf, a0, 0,0,0);
                a1 = __builtin_amdgcn_mfma_f32_16x16x32_f16(w1f[1][kt], bf, a1, 0,0,0);
                a2 = __builtin_amdgcn_mfma_f32_16x16x32_f16(w1f[2][kt], bf, a2, 0,0,0);
                a3 = __builtin_amdgcn_mfma_f32_16x16x32_f16(w1f[3][kt], bf, a3, 0,0,0);
            }
            half8 xb;
            #pragma unroll
            for (int b = 0; b < 8; b++) xb[b] = (_Float16)0.f;
            float xv = x_lds[node*25 + t];
            if (grp == 0){ xb[0] = (_Float16)xv; xb[1] = (_Float16)1.0f; }
            a0 = __builtin_amdgcn_mfma_f32_16x16x32_f16(w1f[0][2], xb, a0, 0,0,0);
            a1 = __builtin_amdgcn_mfma_f32_16x16x32_f16(w1f[1][2], xb, a1, 0,0,0);
            a2 = __builtin_amdgcn_mfma_f32_16x16x32_f16(w1f[2][2], xb, a2, 0,0,0);
            a3 = __builtin_amdgcn_mfma_f32_16x16x32_f16(w1f[3][2], xb, a3, 0,0,0);
            half4_t hp;
            #pragma unroll
            for (int r = 0; r < 4; r++){
                float zi = a0[r], zf = a1[r], zg = a2[r], zo = a3[r];
                float c = sigm(zf)*c1s[nt*4+r] + sigm(zi)*tanh_f(zg);
                c1s[nt*4+r] = c;
                hp[r] = (_Float16)(sigm(zo)*tanh_f(c));
            }
            st1[nt] = hp;
        }
        __syncthreads();
        #pragma unroll
        for (int nt = 0; nt < 4; nt++){
            int node = nt*16 + col;
            *(half4_t*)&h_lds[node*136 + wv*16 + grp*4] = st1[nt];
        }
        __syncthreads();
        // ---------- layer 2 ----------
        half4_t st2[4];
        #pragma unroll
        for (int nt = 0; nt < 4; nt++){
            int node = nt*16 + col;
            floatx4 a0 = {0,0,0,0}, a1 = {0,0,0,0}, a2 = {0,0,0,0}, a3 = {0,0,0,0};
            #pragma unroll
            for (int kt = 0; kt < 4; kt++){
                half8 bf = *(const half8*)&h_lds[node*136 + kt*32 + grp*8];
                a0 = __builtin_amdgcn_mfma_f32_16x16x32_f16(w2f[0][kt], bf, a0, 0,0,0);
                a1 = __builtin_amdgcn_mfma_f32_16x16x32_f16(w2f[1][kt], bf, a1, 0,0,0);
                a2 = __builtin_amdgcn_mfma_f32_16x16x32_f16(w2f[2][kt], bf, a2, 0,0,0);
                a3 = __builtin_amdgcn_mfma_f32_16x16x32_f16(w2f[3][kt], bf, a3, 0,0,0);
            }
            a0 = __builtin_amdgcn_mfma_f32_16x16x32_f16(w2f[0][4], cb, a0, 0,0,0);
            a1 = __builtin_amdgcn_mfma_f32_16x16x32_f16(w2f[1][4], cb, a1, 0,0,0);
            a2 = __builtin_amdgcn_mfma_f32_16x16x32_f16(w2f[2][4], cb, a2, 0,0,0);
            a3 = __builtin_amdgcn_mfma_f32_16x16x32_f16(w2f[3][4], cb, a3, 0,0,0);
            half4_t hp;
            #pragma unroll
            for (int r = 0; r < 4; r++){
                float zi = a0[r], zf = a1[r], zg = a2[r], zo = a3[r];
                float c = sigm(zf)*c2s[nt*4+r] + sigm(zi)*tanh_f(zg);
                c2s[nt*4+r] = c;
                hp[r] = (_Float16)(sigm(zo)*tanh_f(c));
            }
            st2[nt] = hp;
        }
        __syncthreads();
        #pragma unroll
        for (int nt = 0; nt < 4; nt++){
            int node = nt*16 + col;
            *(half4_t*)&h_lds[node*136 + 64 + wv*16 + grp*4] = st2[nt];
        }
        __syncthreads();
    }

    // ---------- GAT projection: x = h2 @ glw^T via MFMA ----------
    const half8* W3Fv = (const half8*)W3F;
    half8 w3f0 = W3Fv[(wv*2+0)*64 + lane];
    half8 w3f1 = W3Fv[(wv*2+1)*64 + lane];
    #pragma unroll
    for (int nt = 0; nt < 4; nt++){
        int node = nt*16 + col;
        floatx4 pa = {0,0,0,0};
        half8 bf0 = *(const half8*)&h_lds[node*136 + 64 + grp*8];
        half8 bf1 = *(const half8*)&h_lds[node*136 + 96 + grp*8];
        pa = __builtin_amdgcn_mfma_f32_16x16x32_f16(w3f0, bf0, pa, 0,0,0);
        pa = __builtin_amdgcn_mfma_f32_16x16x32_f16(w3f1, bf1, pa, 0,0,0);
        *(floatx4*)&xp_lds[node*68 + wv*16 + grp*4] = pa;
    }
    __syncthreads();

    // ---------- attention dots + global writes ----------
    float aw = atts[lane], dw = attd[lane];
    for (int i = 0; i < 16; i++){
        int node = wv*16 + i;
        int nd = node0 + node;
        float v = xp_lds[node*68 + lane];
        float s = v*aw, d2 = v*dw;
        #pragma unroll
        for (int off = 1; off < 16; off <<= 1){ s += __shfl_xor(s, off, 16); d2 += __shfl_xor(d2, off, 16); }
        if (nd < nn){
            x_out[(size_t)nd*64 + lane] = v;
            if ((lane & 15) == 0){ a_src[nd*4 + (lane>>4)] = s; a_dst[nd*4 + (lane>>4)] = d2; }
        }
    }
}

// ---------------- edge pass 1: segment max via atomicMax ----------------
__global__ __launch_bounds__(256) void edge_max_kernel(
    const int* __restrict__ ei, const float* __restrict__ ea, const void* __restrict__ maskp,
    const int* __restrict__ flag, const float* __restrict__ a_src, const float* __restrict__ a_dst,
    const float* __restrict__ ke, unsigned* __restrict__ amax, int E)
{
    int e = blockIdx.x*256 + threadIdx.x;
    if (e >= E) return;
    bool m = (*flag) ? (((const int*)maskp)[e] != 0) : (((const unsigned char*)maskp)[e] != 0);
    if (!m) return;
    int s = ei[e], d = ei[E + e];
    float eav = ea[e];
    float4 as4 = *(const float4*)(a_src + 4*s);
    float4 ad4 = *(const float4*)(a_dst + 4*d);
    float a0 = as4.x + ad4.x + eav*ke[0]; a0 = a0 > 0.f ? a0 : NSLOPE*a0;
    float a1 = as4.y + ad4.y + eav*ke[1]; a1 = a1 > 0.f ? a1 : NSLOPE*a1;
    float a2 = as4.z + ad4.z + eav*ke[2]; a2 = a2 > 0.f ? a2 : NSLOPE*a2;
    float a3 = as4.w + ad4.w + eav*ke[3]; a3 = a3 > 0.f ? a3 : NSLOPE*a3;
    atomicMax(amax + 4*d + 0, fenc(a0));
    atomicMax(amax + 4*d + 1, fenc(a1));
    atomicMax(amax + 4*d + 2, fenc(a2));
    atomicMax(amax + 4*d + 3, fenc(a3));
}

// ---------------- edge pass 2: ex = exp(alpha - amax[dst]); denom += ex ----------------
__global__ __launch_bounds__(256) void edge_ex_kernel(
    const int* __restrict__ ei, const float* __restrict__ ea, const void* __restrict__ maskp,
    const int* __restrict__ flag, const float* __restrict__ a_src, const float* __restrict__ a_dst,
    const float* __restrict__ ke, const unsigned* __restrict__ amax,
    float* __restrict__ denom, float* __restrict__ exb, int E)
{
    int e = blockIdx.x*256 + threadIdx.x;
    if (e >= E) return;
    float4 exv = make_float4(0.f, 0.f, 0.f, 0.f);
    bool m = (*flag) ? (((const int*)maskp)[e] != 0) : (((const unsigned char*)maskp)[e] != 0);
    if (m){
        int s = ei[e], d = ei[E + e];
        float eav = ea[e];
        float4 as4 = *(const float4*)(a_src + 4*s);
        float4 ad4 = *(const float4*)(a_dst + 4*d);
        float a0 = as4.x + ad4.x + eav*ke[0]; a0 = a0 > 0.f ? a0 : NSLOPE*a0;
        float a1 = as4.y + ad4.y + eav*ke[1]; a1 = a1 > 0.f ? a1 : NSLOPE*a1;
        float a2 = as4.z + ad4.z + eav*ke[2]; a2 = a2 > 0.f ? a2 : NSLOPE*a2;
        float a3 = as4.w + ad4.w + eav*ke[3]; a3 = a3 > 0.f ? a3 : NSLOPE*a3;
        exv.x = __expf(a0 - fdec(amax[4*d + 0]));
        exv.y = __expf(a1 - fdec(amax[4*d + 1]));
        exv.z = __expf(a2 - fdec(amax[4*d + 2]));
        exv.w = __expf(a3 - fdec(amax[4*d + 3]));
        atomicAdd(denom + 4*d + 0, exv.x);
        atomicAdd(denom + 4*d + 1, exv.y);
        atomicAdd(denom + 4*d + 2, exv.z);
        atomicAdd(denom + 4*d + 3, exv.w);
    }
    *(float4*)(exb + 4*(size_t)e) = exv;
}

// ---------------- edge pass 3: out[dst] += ex * x[src] ----------------
__global__ __launch_bounds__(256) void edge_msg_kernel(
    const int* __restrict__ ei, const float* __restrict__ exb, const float* __restrict__ xf,
    float* __restrict__ outb, int E)
{
    int t = blockIdx.x*256 + threadIdx.x;
    int e = t >> 4;
    int l = t & 15;
    if (e >= E) return;
    float ev = exb[4*(size_t)e + (l >> 2)];
    if (ev == 0.f) return;
    int s = ei[e], d = ei[E + e];
    float4 xv = *(const float4*)(xf + 64*(size_t)s + 4*l);
    atomicAdd(outb + 64*(size_t)d + 4*l + 0, xv.x*ev);
    atomicAdd(outb + 64*(size_t)d + 4*l + 1, xv.y*ev);
    atomicAdd(outb + 64*(size_t)d + 4*l + 2, xv.z*ev);
    atomicAdd(outb + 64*(size_t)d + 4*l + 3, xv.w*ev);
}

// ---------------- finalize: normalize, +bias, elu, fc dot ----------------
__global__ __launch_bounds__(256) void finalize_kernel(
    const float* __restrict__ outb, const float* __restrict__ denom,
    const float* __restrict__ gbias, const float* __restrict__ fcw, const float* __restrict__ fcb,
    float* __restrict__ y, int nn)
{
    int wave = threadIdx.x >> 6, lane = threadIdx.x & 63;
    int node = blockIdx.x*4 + wave;
    if (node >= nn) return;
    float den = fmaxf(denom[node*4 + (lane >> 4)], 1e-16f);
    float v = outb[64*(size_t)node + lane] / den + gbias[lane];
    v = v > 0.f ? v : (__expf(v) - 1.f);
    float acc = v * fcw[lane];
    #pragma unroll
    for (int off = 1; off < 64; off <<= 1) acc += __shfl_xor(acc, off, 64);
    if (lane == 0) y[node] = acc + fcb[0];
}

extern "C" void kernel_launch(void* const* d_in, const int* in_sizes, int n_in,
                              void* d_out, int out_size, void* d_ws, size_t ws_size,
                              hipStream_t stream)
{
    const float* x_in  = (const float*)d_in[0];
    const int*   ei    = (const int*)d_in[1];
    const float* ea    = (const float*)d_in[2];
    const void*  mask  = d_in[3];
    const float* W_ih1 = (const float*)d_in[4];
    const float* W_hh1 = (const float*)d_in[5];
    const float* b_ih1 = (const float*)d_in[6];
    const float* b_hh1 = (const float*)d_in[7];
    const float* W_ih2 = (const float*)d_in[8];
    const float* W_hh2 = (const float*)d_in[9];
    const float* b_ih2 = (const float*)d_in[10];
    const float* b_hh2 = (const float*)d_in[11];
    const float* glw   = (const float*)d_in[12];
    const float* glew  = (const float*)d_in[13];
    const float* atts  = (const float*)d_in[14];
    const float* attd  = (const float*)d_in[15];
    const float* atte  = (const float*)d_in[16];
    const float* gbias = (const float*)d_in[17];
    const float* fcw   = (const float*)d_in[18];
    const float* fcb   = (const float*)d_in[19];

    const int NN = in_sizes[0] / T_STEPS;
    const int E  = in_sizes[1] / 2;

    float* ws = (float*)d_ws;
    size_t o = 0;
    _Float16* W1F = (_Float16*)(ws + o); o += 24576/2;   // 24576 halves
    _Float16* W2F = (_Float16*)(ws + o); o += 40960/2;
    _Float16* W3F = (_Float16*)(ws + o); o += 4096/2;
    float* ke  = ws + o; o += 64;
    int*  flag = (int*)(ws + o); o += 64;
    float* asrc= ws + o; o += (size_t)NN*4;
    float* adst= ws + o; o += (size_t)NN*4;
    unsigned* amax = (unsigned*)(ws + o); o += (size_t)NN*4;
    float* denom = ws + o; o += (size_t)NN*4;
    float* outb  = ws + o; o += (size_t)NN*64;
    float* xf    = ws + o; o += (size_t)NN*64;
    float* exb   = ws + o; o += (size_t)E*4;

    hipMemsetAsync(amax, 0, ((size_t)NN*4 + (size_t)NN*4 + (size_t)NN*64)*sizeof(float), stream);

    prep_kernel<<<64, 256, 0, stream>>>(W_ih1, W_hh1, b_ih1, b_hh1, W_ih2, W_hh2, b_ih2, b_hh2,
                                        glw, glew, atte, (const unsigned char*)mask,
                                        W1F, W2F, W3F, ke, flag);
    lstm_kernel<<<(NN + 63)/64, 256, 0, stream>>>(x_in, W1F, W2F, W3F,
                                                  atts, attd, xf, asrc, adst, NN);
    edge_max_kernel<<<(E + 255)/256, 256, 0, stream>>>(ei, ea, mask, flag, asrc, adst, ke, amax, E);
    edge_ex_kernel<<<(E + 255)/256, 256, 0, stream>>>(ei, ea, mask, flag, asrc, adst, ke, amax, denom, exb, E);
    edge_msg_kernel<<<(E + 15)/16, 256, 0, stream>>>(ei, exb, xf, outb, E);
    finalize_kernel<<<(NN + 3)/4, 256, 0, stream>>>(outb, denom, gbias, fcw, fcb, (float*)d_out, NN);
}

// Round 3
// 1287.624 us; speedup vs baseline: 6.3956x; 1.6190x over previous
//
#include <hip/hip_runtime.h>
#include <hip/hip_bf16.h>

#define T_STEPS 24
#define NSLOPE 0.2f
#define PITCH 152   // h_lds row pitch in halves: 304B = 19 x 16B granules (odd -> conflict-friendly)

typedef _Float16 half8 __attribute__((ext_vector_type(8)));
typedef _Float16 half4_t __attribute__((ext_vector_type(4)));
typedef float floatx4 __attribute__((ext_vector_type(4)));

__device__ __forceinline__ float sigm(float x){ return __builtin_amdgcn_rcpf(1.0f + __expf(-x)); }
__device__ __forceinline__ float tanh_f(float x){ return 2.0f*__builtin_amdgcn_rcpf(1.0f + __expf(-2.0f*x)) - 1.0f; }

// ---------------- prep: build fp16 MFMA A-fragments, bias C-init, edge consts, mask-dtype flag ----------------
// A-frag lane layout (16x16x32): row = lane&15, k = (lane>>4)*8 + b.
__global__ __launch_bounds__(256) void prep_kernel(
    const float* __restrict__ W_ih1, const float* __restrict__ W_hh1,
    const float* __restrict__ b_ih1, const float* __restrict__ b_hh1,
    const float* __restrict__ W_ih2, const float* __restrict__ W_hh2,
    const float* __restrict__ b_ih2, const float* __restrict__ b_hh2,
    const float* __restrict__ glw, const float* __restrict__ glew,
    const float* __restrict__ atte, const unsigned char* __restrict__ mask_bytes,
    _Float16* __restrict__ W1F, _Float16* __restrict__ W2F, _Float16* __restrict__ W3F,
    float* __restrict__ b2P, float* __restrict__ ke, int* __restrict__ flag)
{
    int tid = blockIdx.x*blockDim.x + threadIdx.x;
    int nth = gridDim.x*blockDim.x;
    // W1F: [w][m][kt<3][lane][b]  — layer1, K = [h1(64) | x,1,pad30]
    for (int idx = tid; idx < 24576; idx += nth){
        int b = idx & 7, t1 = idx >> 3; int lane = t1 & 63, t2 = t1 >> 6;
        int kt = t2 % 3, t3 = t2 / 3; int m = t3 & 3, w = t3 >> 2;
        int row = m*64 + 16*w + (lane & 15);
        float val;
        if (kt < 2){ val = W_hh1[row*64 + 32*kt + (lane>>4)*8 + b]; }
        else { int kin = (lane>>4)*8 + b;
               val = (kin == 0) ? W_ih1[row] : (kin == 1) ? (b_ih1[row]+b_hh1[row]) : 0.f; }
        W1F[idx] = (_Float16)val;
    }
    // W2F: [w][m][kt<4][lane][b] — layer2, K = [h1(64) | h2(64)] (bias via C-init)
    for (int idx = tid; idx < 32768; idx += nth){
        int b = idx & 7;
        int lane = (idx >> 3) & 63;
        int kt = (idx >> 9) & 3;
        int m  = (idx >> 11) & 3;
        int w  = idx >> 13;
        int row = m*64 + 16*w + (lane & 15);
        int k = 32*kt + (lane>>4)*8 + b;
        W2F[idx] = (_Float16)((k < 64) ? W_ih2[row*64 + k] : W_hh2[row*64 + (k-64)]);
    }
    // W3F: [w][kt<2][lane][b] — GAT projection, out-ch rows 16w..16w+15, K = h2(64)
    for (int idx = tid; idx < 4096; idx += nth){
        int b = idx & 7, t1 = idx >> 3; int lane = t1 & 63, t2 = t1 >> 6;
        int kt = t2 & 1, w = t2 >> 1;
        int row = 16*w + (lane & 15);
        W3F[idx] = (_Float16)glw[row*64 + 32*kt + (lane>>4)*8 + b];
    }
    // b2P: [w][m][lane][r] — layer2 bias in C-frag layout (row_local = grp*4+r)
    for (int idx = tid; idx < 4096; idx += nth){
        int r = idx & 3;
        int lane = (idx >> 2) & 63;
        int m = (idx >> 8) & 3;
        int w = idx >> 10;
        int ch = 16*w + (lane >> 4)*4 + r;
        int row = m*64 + ch;
        b2P[idx] = b_ih2[row] + b_hh2[row];
    }
    if (tid < 4){ float s = 0.f; for (int c = 0; c < 16; c++) s += atte[tid*16+c]*glew[tid*16+c]; ke[tid] = s; }
    if (tid == 0){ int nz = 0;
        for (int i = 0; i < 4096; i++){ if ((i&3) != 0 && mask_bytes[i] != 0) nz++; }
        *flag = (nz == 0) ? 1 : 0; }
}

// ---------------- fused MFMA LSTM + GAT projection + attention dots ----------------
// block = 256 threads = 4 waves, 64 nodes. Wave w owns channels [16w,16w+16) x 4 gates,
// processing all 64 nodes (4 N-tiles). Weights persist in VGPRs. h via LDS.
__global__ __launch_bounds__(256, 2) void lstm_kernel(
    const float* __restrict__ x_in,
    const _Float16* __restrict__ W1F, const _Float16* __restrict__ W2F, const _Float16* __restrict__ W3F,
    const float* __restrict__ b2P,
    const float* __restrict__ atts, const float* __restrict__ attd,
    float* __restrict__ x_out, float* __restrict__ a_src, float* __restrict__ a_dst, int nn)
{
    __shared__ _Float16 h_lds[64*PITCH];   // [node][PITCH]: ch 0..63 = h1, 64..127 = h2
    __shared__ _Float16 x_lds[64*26];      // fp16 staged input, pitch 26

    const int wv   = threadIdx.x >> 6;
    const int lane = threadIdx.x & 63;
    const int grp  = lane >> 4;
    const int col  = lane & 15;
    const int node0 = blockIdx.x * 64;

    // stage x (convert to fp16) and zero h
    for (int i = threadIdx.x; i < 64*T_STEPS; i += 256){
        int node = i / T_STEPS, t = i % T_STEPS;
        int nd = node0 + node;
        x_lds[node*26 + t] = (_Float16)((nd < nn) ? x_in[nd*T_STEPS + t] : 0.f);
    }
    for (int i = threadIdx.x; i < 64*PITCH/2; i += 256) ((float*)h_lds)[i] = 0.f;

    // persistent weight fragments
    const half8* W1Fv = (const half8*)W1F;
    const half8* W2Fv = (const half8*)W2F;
    half8 w1f[4][3], w2f[4][4];
    floatx4 b2v[4];
    #pragma unroll
    for (int m = 0; m < 4; m++){
        #pragma unroll
        for (int kt = 0; kt < 3; kt++) w1f[m][kt] = W1Fv[((wv*4+m)*3+kt)*64 + lane];
        #pragma unroll
        for (int kt = 0; kt < 4; kt++) w2f[m][kt] = W2Fv[((wv*4+m)*4+kt)*64 + lane];
        b2v[m] = *(const floatx4*)&b2P[((wv*4+m)*64 + lane)*4];
    }

    float c1s[16], c2s[16];
    #pragma unroll
    for (int i = 0; i < 16; i++){ c1s[i] = 0.f; c2s[i] = 0.f; }

    __syncthreads();

    for (int t = 0; t < T_STEPS; t++){
        // ---------- layer 1 ----------
        half4_t st1[4];
        #pragma unroll
        for (int nt = 0; nt < 4; nt++){
            int node = nt*16 + col;
            floatx4 a0 = {0,0,0,0}, a1 = {0,0,0,0}, a2 = {0,0,0,0}, a3 = {0,0,0,0};
            #pragma unroll
            for (int kt = 0; kt < 2; kt++){
                half8 bf = *(const half8*)&h_lds[node*PITCH + kt*32 + grp*8];
                a0 = __builtin_amdgcn_mfma_f32_16x16x32_f16(w1f[0][kt], bf, a0, 0,0,0);
                a1 = __builtin_amdgcn_mfma_f32_16x16x32_f16(w1f[1][kt], bf, a1, 0,0,0);
                a2 = __builtin_amdgcn_mfma_f32_16x16x32_f16(w1f[2][kt], bf, a2, 0,0,0);
                a3 = __builtin_amdgcn_mfma_f32_16x16x32_f16(w1f[3][kt], bf, a3, 0,0,0);
            }
            half8 xb;
            #pragma unroll
            for (int b = 0; b < 8; b++) xb[b] = (_Float16)0.f;
            _Float16 xv = x_lds[node*26 + t];
            if (grp == 0){ xb[0] = xv; xb[1] = (_Float16)1.0f; }
            a0 = __builtin_amdgcn_mfma_f32_16x16x32_f16(w1f[0][2], xb, a0, 0,0,0);
            a1 = __builtin_amdgcn_mfma_f32_16x16x32_f16(w1f[1][2], xb, a1, 0,0,0);
            a2 = __builtin_amdgcn_mfma_f32_16x16x32_f16(w1f[2][2], xb, a2, 0,0,0);
            a3 = __builtin_amdgcn_mfma_f32_16x16x32_f16(w1f[3][2], xb, a3, 0,0,0);
            half4_t hp;
            #pragma unroll
            for (int r = 0; r < 4; r++){
                float c = sigm(a1[r])*c1s[nt*4+r] + sigm(a0[r])*tanh_f(a2[r]);
                c1s[nt*4+r] = c;
                hp[r] = (_Float16)(sigm(a3[r])*tanh_f(c));
            }
            st1[nt] = hp;
        }
        __syncthreads();
        #pragma unroll
        for (int nt = 0; nt < 4; nt++){
            int node = nt*16 + col;
            *(half4_t*)&h_lds[node*PITCH + wv*16 + grp*4] = st1[nt];
        }
        __syncthreads();
        // ---------- layer 2 ----------
        half4_t st2[4];
        #pragma unroll
        for (int nt = 0; nt < 4; nt++){
            int node = nt*16 + col;
            floatx4 a0 = b2v[0], a1 = b2v[1], a2 = b2v[2], a3 = b2v[3];
            #pragma unroll
            for (int kt = 0; kt < 4; kt++){
                half8 bf = *(const half8*)&h_lds[node*PITCH + kt*32 + grp*8];
                a0 = __builtin_amdgcn_mfma_f32_16x16x32_f16(w2f[0][kt], bf, a0, 0,0,0);
                a1 = __builtin_amdgcn_mfma_f32_16x16x32_f16(w2f[1][kt], bf, a1, 0,0,0);
                a2 = __builtin_amdgcn_mfma_f32_16x16x32_f16(w2f[2][kt], bf, a2, 0,0,0);
                a3 = __builtin_amdgcn_mfma_f32_16x16x32_f16(w2f[3][kt], bf, a3, 0,0,0);
            }
            half4_t hp;
            #pragma unroll
            for (int r = 0; r < 4; r++){
                float c = sigm(a1[r])*c2s[nt*4+r] + sigm(a0[r])*tanh_f(a2[r]);
                c2s[nt*4+r] = c;
                hp[r] = (_Float16)(sigm(a3[r])*tanh_f(c));
            }
            st2[nt] = hp;
        }
        __syncthreads();
        #pragma unroll
        for (int nt = 0; nt < 4; nt++){
            int node = nt*16 + col;
            *(half4_t*)&h_lds[node*PITCH + 64 + wv*16 + grp*4] = st2[nt];
        }
        __syncthreads();
    }

    // ---------- GAT projection + attention dots (no extra LDS: wave w = head w) ----------
    const half8* W3Fv = (const half8*)W3F;
    half8 w3f0 = W3Fv[(wv*2+0)*64 + lane];
    half8 w3f1 = W3Fv[(wv*2+1)*64 + lane];
    float asw[4], adw[4];
    #pragma unroll
    for (int r = 0; r < 4; r++){ int ch = 16*wv + grp*4 + r; asw[r] = atts[ch]; adw[r] = attd[ch]; }
    #pragma unroll
    for (int nt = 0; nt < 4; nt++){
        int node = nt*16 + col;
        int nd = node0 + node;
        floatx4 pa = {0,0,0,0};
        half8 bf0 = *(const half8*)&h_lds[node*PITCH + 64 + grp*8];
        half8 bf1 = *(const half8*)&h_lds[node*PITCH + 96 + grp*8];
        pa = __builtin_amdgcn_mfma_f32_16x16x32_f16(w3f0, bf0, pa, 0,0,0);
        pa = __builtin_amdgcn_mfma_f32_16x16x32_f16(w3f1, bf1, pa, 0,0,0);
        float s  = pa[0]*asw[0] + pa[1]*asw[1] + pa[2]*asw[2] + pa[3]*asw[3];
        float dv = pa[0]*adw[0] + pa[1]*adw[1] + pa[2]*adw[2] + pa[3]*adw[3];
        s  += __shfl_xor(s, 16);  s  += __shfl_xor(s, 32);
        dv += __shfl_xor(dv, 16); dv += __shfl_xor(dv, 32);
        if (nd < nn){
            *(float4*)(x_out + (size_t)nd*64 + 16*wv + grp*4) = make_float4(pa[0], pa[1], pa[2], pa[3]);
            if (grp == 0) a_src[nd*4 + wv] = s;
            else if (grp == 1) a_dst[nd*4 + wv] = dv;
        }
    }
}

// ---------------- fused edge pass: alpha -> exp (no max-sub; |alpha| <~ 0.5) -> denom + messages ----------------
// 16 lanes per edge; lane l handles channels 4l..4l+3, head h = l>>2.
__global__ __launch_bounds__(256) void edge_fused_kernel(
    const int* __restrict__ ei, const float* __restrict__ ea, const void* __restrict__ maskp,
    const int* __restrict__ flag, const float* __restrict__ a_src, const float* __restrict__ a_dst,
    const float* __restrict__ ke, float* __restrict__ denom, float* __restrict__ outb,
    const float* __restrict__ xf, int E)
{
    int t = blockIdx.x*256 + threadIdx.x;
    int e = t >> 4;
    if (e >= E) return;
    int l = t & 15;
    bool m = (*flag) ? (((const int*)maskp)[e] != 0) : (((const unsigned char*)maskp)[e] != 0);
    if (!m) return;
    int s = ei[e], d = ei[E + e];
    int h = l >> 2;
    float a = a_src[4*s + h] + a_dst[4*d + h] + ea[e]*ke[h];
    a = a > 0.f ? a : NSLOPE*a;
    float ev = __expf(a);
    if ((l & 3) == 0) atomicAdd(denom + 4*d + h, ev);
    float4 xv = *(const float4*)(xf + 64*(size_t)s + 4*l);
    atomicAdd(outb + 64*(size_t)d + 4*l + 0, xv.x*ev);
    atomicAdd(outb + 64*(size_t)d + 4*l + 1, xv.y*ev);
    atomicAdd(outb + 64*(size_t)d + 4*l + 2, xv.z*ev);
    atomicAdd(outb + 64*(size_t)d + 4*l + 3, xv.w*ev);
}

// ---------------- finalize: normalize, +bias, elu, fc dot ----------------
__global__ __launch_bounds__(256) void finalize_kernel(
    const float* __restrict__ outb, const float* __restrict__ denom,
    const float* __restrict__ gbias, const float* __restrict__ fcw, const float* __restrict__ fcb,
    float* __restrict__ y, int nn)
{
    int wave = threadIdx.x >> 6, lane = threadIdx.x & 63;
    int node = blockIdx.x*4 + wave;
    if (node >= nn) return;
    float den = fmaxf(denom[node*4 + (lane >> 4)], 1e-16f);
    float v = outb[64*(size_t)node + lane]*__builtin_amdgcn_rcpf(den) + gbias[lane];
    v = v > 0.f ? v : (__expf(v) - 1.f);
    float acc = v * fcw[lane];
    #pragma unroll
    for (int off = 1; off < 64; off <<= 1) acc += __shfl_xor(acc, off, 64);
    if (lane == 0) y[node] = acc + fcb[0];
}

extern "C" void kernel_launch(void* const* d_in, const int* in_sizes, int n_in,
                              void* d_out, int out_size, void* d_ws, size_t ws_size,
                              hipStream_t stream)
{
    const float* x_in  = (const float*)d_in[0];
    const int*   ei    = (const int*)d_in[1];
    const float* ea    = (const float*)d_in[2];
    const void*  mask  = d_in[3];
    const float* W_ih1 = (const float*)d_in[4];
    const float* W_hh1 = (const float*)d_in[5];
    const float* b_ih1 = (const float*)d_in[6];
    const float* b_hh1 = (const float*)d_in[7];
    const float* W_ih2 = (const float*)d_in[8];
    const float* W_hh2 = (const float*)d_in[9];
    const float* b_ih2 = (const float*)d_in[10];
    const float* b_hh2 = (const float*)d_in[11];
    const float* glw   = (const float*)d_in[12];
    const float* glew  = (const float*)d_in[13];
    const float* atts  = (const float*)d_in[14];
    const float* attd  = (const float*)d_in[15];
    const float* atte  = (const float*)d_in[16];
    const float* gbias = (const float*)d_in[17];
    const float* fcw   = (const float*)d_in[18];
    const float* fcb   = (const float*)d_in[19];

    const int NN = in_sizes[0] / T_STEPS;
    const int E  = in_sizes[1] / 2;

    float* ws = (float*)d_ws;
    size_t o = 0;
    _Float16* W1F = (_Float16*)(ws + o); o += 24576/2;
    _Float16* W2F = (_Float16*)(ws + o); o += 32768/2;
    _Float16* W3F = (_Float16*)(ws + o); o += 4096/2;
    float* b2P = ws + o; o += 4096;
    float* ke  = ws + o; o += 64;
    int*  flag = (int*)(ws + o); o += 64;
    float* asrc= ws + o; o += (size_t)NN*4;
    float* adst= ws + o; o += (size_t)NN*4;
    float* denom = ws + o; o += (size_t)NN*4;
    float* outb  = ws + o; o += (size_t)NN*64;
    float* xf    = ws + o; o += (size_t)NN*64;

    // zero denom|outb (contiguous)
    hipMemsetAsync(denom, 0, ((size_t)NN*4 + (size_t)NN*64)*sizeof(float), stream);

    prep_kernel<<<64, 256, 0, stream>>>(W_ih1, W_hh1, b_ih1, b_hh1, W_ih2, W_hh2, b_ih2, b_hh2,
                                        glw, glew, atte, (const unsigned char*)mask,
                                        W1F, W2F, W3F, b2P, ke, flag);
    lstm_kernel<<<(NN + 63)/64, 256, 0, stream>>>(x_in, W1F, W2F, W3F, b2P,
                                                  atts, attd, xf, asrc, adst, NN);
    edge_fused_kernel<<<(E*16 + 255)/256, 256, 0, stream>>>(ei, ea, mask, flag, asrc, adst, ke,
                                                            denom, outb, xf, E);
    finalize_kernel<<<(NN + 3)/4, 256, 0, stream>>>(outb, denom, gbias, fcw, fcb, (float*)d_out, NN);
}

// Round 4
// 818.866 us; speedup vs baseline: 10.0568x; 1.5724x over previous
//
#include <hip/hip_runtime.h>
#include <hip/hip_bf16.h>

#define T_STEPS 24
#define NSLOPE 0.2f
#define PITCH 152   // h_lds row pitch in halves

typedef _Float16 half8 __attribute__((ext_vector_type(8)));
typedef _Float16 half4_t __attribute__((ext_vector_type(4)));
typedef float floatx4 __attribute__((ext_vector_type(4)));

__device__ __forceinline__ float sigm(float x){ return __builtin_amdgcn_rcpf(1.0f + __expf(-x)); }
__device__ __forceinline__ float tanh_f(float x){ return 2.0f*__builtin_amdgcn_rcpf(1.0f + __expf(-2.0f*x)) - 1.0f; }

// ---------------- prep: build fp16 MFMA A-fragments, bias C-init, edge consts, mask-dtype flag ----------------
__global__ __launch_bounds__(256) void prep_kernel(
    const float* __restrict__ W_ih1, const float* __restrict__ W_hh1,
    const float* __restrict__ b_ih1, const float* __restrict__ b_hh1,
    const float* __restrict__ W_ih2, const float* __restrict__ W_hh2,
    const float* __restrict__ b_ih2, const float* __restrict__ b_hh2,
    const float* __restrict__ glw, const float* __restrict__ glew,
    const float* __restrict__ atte, const unsigned char* __restrict__ mask_bytes,
    _Float16* __restrict__ W1F, _Float16* __restrict__ W2F, _Float16* __restrict__ W3F,
    float* __restrict__ b2P, float* __restrict__ ke, int* __restrict__ flag)
{
    int tid = blockIdx.x*blockDim.x + threadIdx.x;
    int nth = gridDim.x*blockDim.x;
    for (int idx = tid; idx < 24576; idx += nth){
        int b = idx & 7, t1 = idx >> 3; int lane = t1 & 63, t2 = t1 >> 6;
        int kt = t2 % 3, t3 = t2 / 3; int m = t3 & 3, w = t3 >> 2;
        int row = m*64 + 16*w + (lane & 15);
        float val;
        if (kt < 2){ val = W_hh1[row*64 + 32*kt + (lane>>4)*8 + b]; }
        else { int kin = (lane>>4)*8 + b;
               val = (kin == 0) ? W_ih1[row] : (kin == 1) ? (b_ih1[row]+b_hh1[row]) : 0.f; }
        W1F[idx] = (_Float16)val;
    }
    for (int idx = tid; idx < 32768; idx += nth){
        int b = idx & 7;
        int lane = (idx >> 3) & 63;
        int kt = (idx >> 9) & 3;
        int m  = (idx >> 11) & 3;
        int w  = idx >> 13;
        int row = m*64 + 16*w + (lane & 15);
        int k = 32*kt + (lane>>4)*8 + b;
        W2F[idx] = (_Float16)((k < 64) ? W_ih2[row*64 + k] : W_hh2[row*64 + (k-64)]);
    }
    for (int idx = tid; idx < 4096; idx += nth){
        int b = idx & 7, t1 = idx >> 3; int lane = t1 & 63, t2 = t1 >> 6;
        int kt = t2 & 1, w = t2 >> 1;
        int row = 16*w + (lane & 15);
        W3F[idx] = (_Float16)glw[row*64 + 32*kt + (lane>>4)*8 + b];
    }
    for (int idx = tid; idx < 4096; idx += nth){
        int r = idx & 3;
        int lane = (idx >> 2) & 63;
        int m = (idx >> 8) & 3;
        int w = idx >> 10;
        int ch = 16*w + (lane >> 4)*4 + r;
        int row = m*64 + ch;
        b2P[idx] = b_ih2[row] + b_hh2[row];
    }
    if (tid < 4){ float s = 0.f; for (int c = 0; c < 16; c++) s += atte[tid*16+c]*glew[tid*16+c]; ke[tid] = s; }
    if (tid == 0){ int nz = 0;
        for (int i = 0; i < 4096; i++){ if ((i&3) != 0 && mask_bytes[i] != 0) nz++; }
        *flag = (nz == 0) ? 1 : 0; }
}

// ---------------- CSR build: degree count ----------------
__global__ __launch_bounds__(256) void count_kernel(
    const int* __restrict__ ei, const void* __restrict__ maskp, const int* __restrict__ flag,
    int* __restrict__ deg, int E)
{
    int e = blockIdx.x*256 + threadIdx.x;
    if (e >= E) return;
    bool m = (*flag) ? (((const int*)maskp)[e] != 0) : (((const unsigned char*)maskp)[e] != 0);
    if (!m) return;
    atomicAdd(deg + ei[E + e], 1);
}

// ---------------- CSR build: single-block exclusive scan (1024 threads) ----------------
__global__ __launch_bounds__(1024) void scan_kernel(
    const int* __restrict__ deg, int* __restrict__ offs, int* __restrict__ cursor, int nn)
{
    __shared__ int wsum[16];
    __shared__ int sbase;
    int lane = threadIdx.x & 63, wv = threadIdx.x >> 6;
    if (threadIdx.x == 0) sbase = 0;
    __syncthreads();
    for (int base_i = 0; base_i < nn; base_i += 1024){
        int i = base_i + (int)threadIdx.x;
        int v = (i < nn) ? deg[i] : 0;
        int sc = v;
        #pragma unroll
        for (int o = 1; o < 64; o <<= 1){ int t = __shfl_up(sc, o); if (lane >= o) sc += t; }
        if (lane == 63) wsum[wv] = sc;
        __syncthreads();
        int wbase = 0, total = 0;
        #pragma unroll
        for (int k = 0; k < 16; k++){ int s = wsum[k]; if (k < wv) wbase += s; total += s; }
        int excl = sbase + wbase + sc - v;
        if (i < nn){ offs[i] = excl; cursor[i] = excl; }
        __syncthreads();
        if (threadIdx.x == 0) sbase += total;
        __syncthreads();
    }
    if (threadIdx.x == 0) offs[nn] = sbase;
}

// ---------------- CSR build: scatter (src, edge_attr) records ----------------
__global__ __launch_bounds__(256) void scatter_kernel(
    const int* __restrict__ ei, const float* __restrict__ ea, const void* __restrict__ maskp,
    const int* __restrict__ flag, int* __restrict__ cursor, int2* __restrict__ rec, int E)
{
    int e = blockIdx.x*256 + threadIdx.x;
    if (e >= E) return;
    bool m = (*flag) ? (((const int*)maskp)[e] != 0) : (((const unsigned char*)maskp)[e] != 0);
    if (!m) return;
    int d = ei[E + e];
    int pos = atomicAdd(cursor + d, 1);
    rec[pos] = make_int2(ei[e], __float_as_int(ea[e]));
}

// ---------------- fused MFMA LSTM + GAT projection + attention dots ----------------
__global__ __launch_bounds__(256, 2) void lstm_kernel(
    const float* __restrict__ x_in,
    const _Float16* __restrict__ W1F, const _Float16* __restrict__ W2F, const _Float16* __restrict__ W3F,
    const float* __restrict__ b2P,
    const float* __restrict__ atts, const float* __restrict__ attd,
    float* __restrict__ x_out, float* __restrict__ a_src, float* __restrict__ a_dst, int nn)
{
    __shared__ _Float16 h_lds[64*PITCH];
    __shared__ _Float16 x_lds[64*26];

    const int wv   = threadIdx.x >> 6;
    const int lane = threadIdx.x & 63;
    const int grp  = lane >> 4;
    const int col  = lane & 15;
    const int node0 = blockIdx.x * 64;

    for (int i = threadIdx.x; i < 64*T_STEPS; i += 256){
        int node = i / T_STEPS, t = i % T_STEPS;
        int nd = node0 + node;
        x_lds[node*26 + t] = (_Float16)((nd < nn) ? x_in[nd*T_STEPS + t] : 0.f);
    }
    for (int i = threadIdx.x; i < 64*PITCH/2; i += 256) ((float*)h_lds)[i] = 0.f;

    const half8* W1Fv = (const half8*)W1F;
    const half8* W2Fv = (const half8*)W2F;
    half8 w1f[4][3], w2f[4][4];
    floatx4 b2v[4];
    #pragma unroll
    for (int m = 0; m < 4; m++){
        #pragma unroll
        for (int kt = 0; kt < 3; kt++) w1f[m][kt] = W1Fv[((wv*4+m)*3+kt)*64 + lane];
        #pragma unroll
        for (int kt = 0; kt < 4; kt++) w2f[m][kt] = W2Fv[((wv*4+m)*4+kt)*64 + lane];
        b2v[m] = *(const floatx4*)&b2P[((wv*4+m)*64 + lane)*4];
    }

    float c1s[16], c2s[16];
    #pragma unroll
    for (int i = 0; i < 16; i++){ c1s[i] = 0.f; c2s[i] = 0.f; }

    __syncthreads();

    for (int t = 0; t < T_STEPS; t++){
        half4_t st1[4];
        #pragma unroll
        for (int nt = 0; nt < 4; nt++){
            int node = nt*16 + col;
            floatx4 a0 = {0,0,0,0}, a1 = {0,0,0,0}, a2 = {0,0,0,0}, a3 = {0,0,0,0};
            #pragma unroll
            for (int kt = 0; kt < 2; kt++){
                half8 bf = *(const half8*)&h_lds[node*PITCH + kt*32 + grp*8];
                a0 = __builtin_amdgcn_mfma_f32_16x16x32_f16(w1f[0][kt], bf, a0, 0,0,0);
                a1 = __builtin_amdgcn_mfma_f32_16x16x32_f16(w1f[1][kt], bf, a1, 0,0,0);
                a2 = __builtin_amdgcn_mfma_f32_16x16x32_f16(w1f[2][kt], bf, a2, 0,0,0);
                a3 = __builtin_amdgcn_mfma_f32_16x16x32_f16(w1f[3][kt], bf, a3, 0,0,0);
            }
            half8 xb;
            #pragma unroll
            for (int b = 0; b < 8; b++) xb[b] = (_Float16)0.f;
            _Float16 xv = x_lds[node*26 + t];
            if (grp == 0){ xb[0] = xv; xb[1] = (_Float16)1.0f; }
            a0 = __builtin_amdgcn_mfma_f32_16x16x32_f16(w1f[0][2], xb, a0, 0,0,0);
            a1 = __builtin_amdgcn_mfma_f32_16x16x32_f16(w1f[1][2], xb, a1, 0,0,0);
            a2 = __builtin_amdgcn_mfma_f32_16x16x32_f16(w1f[2][2], xb, a2, 0,0,0);
            a3 = __builtin_amdgcn_mfma_f32_16x16x32_f16(w1f[3][2], xb, a3, 0,0,0);
            half4_t hp;
            #pragma unroll
            for (int r = 0; r < 4; r++){
                float c = sigm(a1[r])*c1s[nt*4+r] + sigm(a0[r])*tanh_f(a2[r]);
                c1s[nt*4+r] = c;
                hp[r] = (_Float16)(sigm(a3[r])*tanh_f(c));
            }
            st1[nt] = hp;
        }
        __syncthreads();
        #pragma unroll
        for (int nt = 0; nt < 4; nt++){
            int node = nt*16 + col;
            *(half4_t*)&h_lds[node*PITCH + wv*16 + grp*4] = st1[nt];
        }
        __syncthreads();
        half4_t st2[4];
        #pragma unroll
        for (int nt = 0; nt < 4; nt++){
            int node = nt*16 + col;
            floatx4 a0 = b2v[0], a1 = b2v[1], a2 = b2v[2], a3 = b2v[3];
            #pragma unroll
            for (int kt = 0; kt < 4; kt++){
                half8 bf = *(const half8*)&h_lds[node*PITCH + kt*32 + grp*8];
                a0 = __builtin_amdgcn_mfma_f32_16x16x32_f16(w2f[0][kt], bf, a0, 0,0,0);
                a1 = __builtin_amdgcn_mfma_f32_16x16x32_f16(w2f[1][kt], bf, a1, 0,0,0);
                a2 = __builtin_amdgcn_mfma_f32_16x16x32_f16(w2f[2][kt], bf, a2, 0,0,0);
                a3 = __builtin_amdgcn_mfma_f32_16x16x32_f16(w2f[3][kt], bf, a3, 0,0,0);
            }
            half4_t hp;
            #pragma unroll
            for (int r = 0; r < 4; r++){
                float c = sigm(a1[r])*c2s[nt*4+r] + sigm(a0[r])*tanh_f(a2[r]);
                c2s[nt*4+r] = c;
                hp[r] = (_Float16)(sigm(a3[r])*tanh_f(c));
            }
            st2[nt] = hp;
        }
        __syncthreads();
        #pragma unroll
        for (int nt = 0; nt < 4; nt++){
            int node = nt*16 + col;
            *(half4_t*)&h_lds[node*PITCH + 64 + wv*16 + grp*4] = st2[nt];
        }
        __syncthreads();
    }

    const half8* W3Fv = (const half8*)W3F;
    half8 w3f0 = W3Fv[(wv*2+0)*64 + lane];
    half8 w3f1 = W3Fv[(wv*2+1)*64 + lane];
    float asw[4], adw[4];
    #pragma unroll
    for (int r = 0; r < 4; r++){ int ch = 16*wv + grp*4 + r; asw[r] = atts[ch]; adw[r] = attd[ch]; }
    #pragma unroll
    for (int nt = 0; nt < 4; nt++){
        int node = nt*16 + col;
        int nd = node0 + node;
        floatx4 pa = {0,0,0,0};
        half8 bf0 = *(const half8*)&h_lds[node*PITCH + 64 + grp*8];
        half8 bf1 = *(const half8*)&h_lds[node*PITCH + 96 + grp*8];
        pa = __builtin_amdgcn_mfma_f32_16x16x32_f16(w3f0, bf0, pa, 0,0,0);
        pa = __builtin_amdgcn_mfma_f32_16x16x32_f16(w3f1, bf1, pa, 0,0,0);
        float s  = pa[0]*asw[0] + pa[1]*asw[1] + pa[2]*asw[2] + pa[3]*asw[3];
        float dv = pa[0]*adw[0] + pa[1]*adw[1] + pa[2]*adw[2] + pa[3]*adw[3];
        s  += __shfl_xor(s, 16);  s  += __shfl_xor(s, 32);
        dv += __shfl_xor(dv, 16); dv += __shfl_xor(dv, 32);
        if (nd < nn){
            *(float4*)(x_out + (size_t)nd*64 + 16*wv + grp*4) = make_float4(pa[0], pa[1], pa[2], pa[3]);
            if (grp == 0) a_src[nd*4 + wv] = s;
            else if (grp == 1) a_dst[nd*4 + wv] = dv;
        }
    }
}

// ---------------- gather: wave-per-node CSR aggregation + fused finalize ----------------
// lane = channel, h = lane>>4. Per edge: broadcast rec, a_src line, coalesced 256B xf read.
__global__ __launch_bounds__(256) void gather_kernel(
    const int2* __restrict__ rec, const int* __restrict__ offs,
    const float* __restrict__ a_src, const float* __restrict__ a_dst, const float* __restrict__ ke,
    const float* __restrict__ xf, const float* __restrict__ gbias,
    const float* __restrict__ fcw, const float* __restrict__ fcb,
    float* __restrict__ y, int nn)
{
    int wv = threadIdx.x >> 6, lane = threadIdx.x & 63;
    int node = blockIdx.x*4 + wv;
    if (node >= nn) return;
    int h = lane >> 4;
    float keh = ke[h];
    float adv = a_dst[4*node + h];
    int beg = offs[node], end = offs[node+1];
    float acc = 0.f, dacc = 0.f;
    for (int j = beg; j < end; ++j){
        int2 r = rec[j];
        int s = r.x;
        float eav = __int_as_float(r.y);
        float a = a_src[4*s + h] + adv + eav*keh;
        a = a > 0.f ? a : NSLOPE*a;
        float ev = __expf(a);
        dacc += ev;
        acc += ev * xf[(size_t)s*64 + lane];
    }
    float v = acc * __builtin_amdgcn_rcpf(fmaxf(dacc, 1e-16f)) + gbias[lane];
    v = v > 0.f ? v : (__expf(v) - 1.f);
    float r2 = v * fcw[lane];
    #pragma unroll
    for (int off = 1; off < 64; off <<= 1) r2 += __shfl_xor(r2, off, 64);
    if (lane == 0) y[node] = r2 + fcb[0];
}

extern "C" void kernel_launch(void* const* d_in, const int* in_sizes, int n_in,
                              void* d_out, int out_size, void* d_ws, size_t ws_size,
                              hipStream_t stream)
{
    const float* x_in  = (const float*)d_in[0];
    const int*   ei    = (const int*)d_in[1];
    const float* ea    = (const float*)d_in[2];
    const void*  mask  = d_in[3];
    const float* W_ih1 = (const float*)d_in[4];
    const float* W_hh1 = (const float*)d_in[5];
    const float* b_ih1 = (const float*)d_in[6];
    const float* b_hh1 = (const float*)d_in[7];
    const float* W_ih2 = (const float*)d_in[8];
    const float* W_hh2 = (const float*)d_in[9];
    const float* b_ih2 = (const float*)d_in[10];
    const float* b_hh2 = (const float*)d_in[11];
    const float* glw   = (const float*)d_in[12];
    const float* glew  = (const float*)d_in[13];
    const float* atts  = (const float*)d_in[14];
    const float* attd  = (const float*)d_in[15];
    const float* atte  = (const float*)d_in[16];
    const float* gbias = (const float*)d_in[17];
    const float* fcw   = (const float*)d_in[18];
    const float* fcb   = (const float*)d_in[19];

    const int NN = in_sizes[0] / T_STEPS;
    const int E  = in_sizes[1] / 2;

    float* ws = (float*)d_ws;
    size_t o = 0;
    _Float16* W1F = (_Float16*)(ws + o); o += 24576/2;
    _Float16* W2F = (_Float16*)(ws + o); o += 32768/2;
    _Float16* W3F = (_Float16*)(ws + o); o += 4096/2;
    float* b2P = ws + o; o += 4096;
    float* ke  = ws + o; o += 64;
    int*  flag = (int*)(ws + o); o += 64;
    float* asrc= ws + o; o += (size_t)NN*4;
    float* adst= ws + o; o += (size_t)NN*4;
    float* xf  = ws + o; o += (size_t)NN*64;
    int* deg    = (int*)(ws + o); o += NN;
    int* offs   = (int*)(ws + o); o += NN + 64;
    int* cursor = (int*)(ws + o); o += NN;
    int2* rec   = (int2*)(ws + o); o += (size_t)E*2;

    hipMemsetAsync(deg, 0, (size_t)NN*sizeof(int), stream);

    prep_kernel<<<64, 256, 0, stream>>>(W_ih1, W_hh1, b_ih1, b_hh1, W_ih2, W_hh2, b_ih2, b_hh2,
                                        glw, glew, atte, (const unsigned char*)mask,
                                        W1F, W2F, W3F, b2P, ke, flag);
    count_kernel<<<(E + 255)/256, 256, 0, stream>>>(ei, mask, flag, deg, E);
    scan_kernel<<<1, 1024, 0, stream>>>(deg, offs, cursor, NN);
    scatter_kernel<<<(E + 255)/256, 256, 0, stream>>>(ei, ea, mask, flag, cursor, rec, E);
    lstm_kernel<<<(NN + 63)/64, 256, 0, stream>>>(x_in, W1F, W2F, W3F, b2P,
                                                  atts, attd, xf, asrc, adst, NN);
    gather_kernel<<<(NN + 3)/4, 256, 0, stream>>>(rec, offs, asrc, adst, ke, xf,
                                                  gbias, fcw, fcb, (float*)d_out, NN);
}